// Round 9
// baseline (474.100 us; speedup 1.0000x reference)
//
#include <hip/hip_runtime.h>
#include <math.h>

#define NB  64
#define TT  1024
#define H2  512      // 2*H
#define SS  128      // style dim
#define OO  80
#define FIN_A 896    // 3H+S (ga_ih inner dim)
#define FIN_1 1152   // 4H+S (wsc / g1_ih inner dim)
#define CH  32       // t-chunks for fused attention

__device__ __forceinline__ float fast_rcp(float x) { return __builtin_amdgcn_rcpf(x); }
__device__ __forceinline__ float fast_sigmoid(float x) { return fast_rcp(1.0f + __expf(-x)); }
// tanh = 1 - 2/(e^{2x}+1); rcp(inf)=0 handles saturation
__device__ __forceinline__ float fast_tanh(float x) {
    float e = __expf(2.0f * x);
    return 1.0f - 2.0f * fast_rcp(e + 1.0f);
}
__device__ __forceinline__ float wred(float p) {
    #pragma unroll
    for (int o = 32; o > 0; o >>= 1) p += __shfl_xor(p, o, 64);
    return p;
}

// ---- Stage 1 (FUSED dec path): per-sample chain t1 -> pre -> out_att -> attW_dec.
// Block = n (64 blocks x 1024 threads = 16 waves). All intermediates in LDS;
// no grid-wide sync needed because every stage only uses batch row n.
__global__ __launch_bounds__(1024) void k_dec(
        const float* __restrict__ xdec, const float* __restrict__ sv,
        const float* __restrict__ pw1, const float* __restrict__ pb1,
        const float* __restrict__ pw2, const float* __restrict__ pb2,
        const float* __restrict__ ga_ih, const float* __restrict__ ga_bih,
        const float* __restrict__ ga_bhh,
        const float* __restrict__ wdec, const float* __restrict__ bdec,
        float* __restrict__ out_decT, float* __restrict__ attW_dec) {
    int n = blockIdx.x;
    int wv = threadIdx.x >> 6, lane = threadIdx.x & 63;   // 16 waves
    __shared__ float st1[512];
    __shared__ float spre[256];
    __shared__ float ssv[128];
    __shared__ float satt[512];

    // sv row -> LDS + out_decT rows 1024..1151
    if (threadIdx.x < 128) {
        float v = sv[n * SS + threadIdx.x];
        ssv[threadIdx.x] = v;
        out_decT[(1024 + threadIdx.x) * 64 + n] = v;
    }

    // A: t1 = relu(xdec[n] @ pw1.T + pb1), 512 outputs, 32 per wave (K=80)
    const float* x0 = xdec + n * OO;
    float xa = (lane < OO) ? x0[lane] : 0.0f;
    float xb = (lane < OO - 64) ? x0[64 + lane] : 0.0f;
    for (int o = 0; o < 32; ++o) {
        int i = wv * 32 + o;
        const float* w = pw1 + i * OO;
        float wa = (lane < OO) ? w[lane] : 0.0f;
        float wb = (lane < OO - 64) ? w[64 + lane] : 0.0f;
        float p = wred(xa * wa + xb * wb);
        if (lane == 0) st1[i] = fmaxf(p + pb1[i], 0.0f);
    }
    __syncthreads();

    // B: pre = relu(t1 @ pw2.T + pb2), 256 outputs, 16 per wave (K=512)
    for (int o = 0; o < 16; ++o) {
        int i = wv * 16 + o;
        const float* w = pw2 + (size_t)i * H2;
        float p = 0.0f;
        #pragma unroll
        for (int m = 0; m < 8; ++m) { int k = lane + 64 * m; p += w[k] * st1[k]; }
        p = wred(p);
        if (lane == 0) spre[i] = fmaxf(p + pb2[i], 0.0f);
    }
    __syncthreads();

    // C: attention GRU (h=0, ctx=0): out_att[512], 32 j per wave (K=384, 3 gates)
    for (int o = 0; o < 32; ++o) {
        int j = wv * 32 + o;
        const float* wr = ga_ih + (size_t)j * FIN_A;
        const float* wz = ga_ih + (size_t)(H2 + j) * FIN_A;
        const float* wn = ga_ih + (size_t)(2 * H2 + j) * FIN_A;
        float pr = 0.0f, pz = 0.0f, pn = 0.0f;
        #pragma unroll
        for (int m = 0; m < 4; ++m) {                  // pre part: k=0..255, wc=k
            int k = lane + 64 * m;
            float xv = spre[k];
            pr += wr[k] * xv; pz += wz[k] * xv; pn += wn[k] * xv;
        }
        #pragma unroll
        for (int m = 0; m < 2; ++m) {                  // sv part: wc=768..895
            int k = lane + 64 * m;
            float xv = ssv[k];
            pr += wr[768 + k] * xv; pz += wz[768 + k] * xv; pn += wn[768 + k] * xv;
        }
        pr = wred(pr); pz = wred(pz); pn = wred(pn);
        if (lane == 0) {
            float r = fast_sigmoid(pr + ga_bih[j] + ga_bhh[j]);
            float z = fast_sigmoid(pz + ga_bih[H2 + j] + ga_bhh[H2 + j]);
            float nn = fast_tanh(pn + ga_bih[2 * H2 + j] + r * ga_bhh[2 * H2 + j]);
            float oa = (1.0f - z) * nn;
            satt[j] = oa;
            out_decT[(H2 + j) * 64 + n] = oa;          // rows 512..1023
        }
    }
    __syncthreads();

    // D: attW_dec[n][i] = out_att @ wdec.T + bdec, 32 i per wave (K=512)
    for (int o = 0; o < 32; ++o) {
        int i = wv * 32 + o;
        const float* w = wdec + (size_t)i * H2;
        float p = 0.0f;
        #pragma unroll
        for (int m = 0; m < 8; ++m) { int k = lane + 64 * m; p += w[k] * satt[k]; }
        p = wred(p);
        if (lane == 0) attW_dec[n * H2 + i] = p + bdec[i];
    }
}

// ---- Stage 2: FUSED score+apply, length-balanced. Block (c,p) handles chunk c of
// n=p and n=63-p (lengths sorted desc -> pair work ~constant). Coalesced num_part.
__global__ __launch_bounds__(256) void k_attn(
        const float* __restrict__ enc, const float* __restrict__ attw_enc,
        const float* __restrict__ attW_dec, const float* __restrict__ wattn,
        const float* __restrict__ battn, const int* __restrict__ lengths,
        float* __restrict__ num_part /*[CH][NB][512]*/,
        float* __restrict__ den_part /*[CH][NB]*/) {
    int p = blockIdx.y;
    int c = blockIdx.x;
    int wv = threadIdx.x >> 6, lane = threadIdx.x & 63;
    int t0 = c * (TT / CH);
    __shared__ float sew[TT / CH];
    __shared__ float s[4 * 512];
    __shared__ float sd[4];
    const float4* w4 = (const float4*)wattn;
    float b = battn[0];

    #pragma unroll
    for (int half = 0; half < 2; ++half) {
        int n = half ? (63 - p) : p;
        int len = lengths[n];
        {
            const float4* d4 = (const float4*)(attW_dec + n * H2);
            #pragma unroll
            for (int r = 0; r < 8; ++r) {
                int t = t0 + wv * 8 + r;
                float val = 0.0f;
                if (t < len) {                       // wave-uniform
                    const float4* e4 = (const float4*)(attw_enc + ((size_t)(n * TT + t)) * H2);
                    float pp = 0.0f;
                    #pragma unroll
                    for (int m = 0; m < 2; ++m) {
                        int idx = lane + m * 64;
                        float4 e = e4[idx], d = d4[idx], w = w4[idx];
                        pp += fast_tanh(e.x + d.x) * w.x + fast_tanh(e.y + d.y) * w.y +
                              fast_tanh(e.z + d.z) * w.z + fast_tanh(e.w + d.w) * w.w;
                    }
                    pp = wred(pp);
                    val = __expf(pp + b);
                }
                if (lane == 0) sew[wv * 8 + r] = val;
            }
        }
        __syncthreads();
        int d0 = lane * 8;
        const float* base = enc + ((size_t)(n * TT + t0 + wv * 8)) * H2 + d0;
        float4 a0 = {0, 0, 0, 0}, a1 = {0, 0, 0, 0};
        float dp = 0.0f;
        #pragma unroll
        for (int r = 0; r < 8; ++r) {
            float wt = sew[wv * 8 + r];
            if (wt != 0.0f) {                        // wave-uniform skip
                const float4* v4 = (const float4*)(base + (size_t)r * H2);
                float4 v0 = v4[0], v1 = v4[1];
                a0.x += wt * v0.x; a0.y += wt * v0.y; a0.z += wt * v0.z; a0.w += wt * v0.w;
                a1.x += wt * v1.x; a1.y += wt * v1.y; a1.z += wt * v1.z; a1.w += wt * v1.w;
                dp += wt;
            }
        }
        float4* srow = (float4*)(s + wv * 512 + d0);
        srow[0] = a0; srow[1] = a1;
        if (lane == 0) sd[wv] = dp;
        __syncthreads();
        int d = threadIdx.x;
        float r0 = s[d] + s[512 + d] + s[1024 + d] + s[1536 + d];
        float r1 = s[256 + d] + s[768 + d] + s[1280 + d] + s[1792 + d];
        float* np = num_part + ((size_t)(c * NB + n)) * H2;
        np[d] = r0;
        np[256 + d] = r1;
        if (threadIdx.x == 0) den_part[c * NB + n] = sd[0] + sd[1] + sd[2] + sd[3];
        __syncthreads();
    }
}

// ---- Stage 3: reduce partials -> attn_applied (output 1) + out_decT rows 0..511
__global__ void k_reduce(const float* __restrict__ num_part, const float* __restrict__ den_part,
                         float* __restrict__ out, float* __restrict__ out_decT) {
    int n = blockIdx.x;
    int d = blockIdx.y * 256 + threadIdx.x;
    float s = 0.0f, den = 0.0f;
    #pragma unroll 8
    for (int c = 0; c < CH; ++c) {
        s += num_part[((size_t)(c * NB + n)) * H2 + d];
        den += den_part[c * NB + n];
    }
    float a = s / fmaxf(den, 1e-12f);
    out[NB * 160 + n * H2 + d] = a;                  // output 1 (n-major)
    out_decT[(size_t)d * 64 + n] = a;                // transposed for GEMM chain
}

// ---- Stage 4: res1T = (out_dec @ wsc.T + bsc + GRU1(out_dec,0))^T. Block per j; 8 waves split K=1152.
__global__ __launch_bounds__(512) void k_sc_h1(const float* __restrict__ out_decT,
                                               const float* __restrict__ wsc,
                                               const float* __restrict__ bsc,
                                               const float* __restrict__ g1_ih,
                                               const float* __restrict__ g1_bih,
                                               const float* __restrict__ g1_bhh,
                                               float* __restrict__ res1T) {
    int j = blockIdx.x;
    int wv = threadIdx.x >> 6, lane = threadIdx.x & 63;
    int k0 = wv * 144;
    const float* ws_ = wsc + (size_t)j * FIN_1 + k0;
    const float* wr = g1_ih + (size_t)j * FIN_1 + k0;
    const float* wz = g1_ih + (size_t)(H2 + j) * FIN_1 + k0;
    const float* wn = g1_ih + (size_t)(2 * H2 + j) * FIN_1 + k0;
    const float* xT = out_decT + k0 * 64;
    float2 ps = {0, 0}, pr = {0, 0}, pz = {0, 0}, pn = {0, 0};
    #pragma unroll 4
    for (int k = 0; k < 144; k += 2) {
        float x0 = xT[k * 64 + lane];
        float x1 = xT[(k + 1) * 64 + lane];
        float2 a = *(const float2*)(ws_ + k);
        float2 bb = *(const float2*)(wr + k);
        float2 cc = *(const float2*)(wz + k);
        float2 dd = *(const float2*)(wn + k);
        ps.x += a.x * x0; ps.y += a.y * x1;
        pr.x += bb.x * x0; pr.y += bb.y * x1;
        pz.x += cc.x * x0; pz.y += cc.y * x1;
        pn.x += dd.x * x0; pn.y += dd.y * x1;
    }
    __shared__ float s[4][8][64];
    s[0][wv][lane] = ps.x + ps.y; s[1][wv][lane] = pr.x + pr.y;
    s[2][wv][lane] = pz.x + pz.y; s[3][wv][lane] = pn.x + pn.y;
    __syncthreads();
    if (wv == 0) {
        float fs = 0.0f, fr = 0.0f, fz = 0.0f, fn = 0.0f;
        #pragma unroll
        for (int q = 0; q < 8; ++q) {
            fs += s[0][q][lane]; fr += s[1][q][lane];
            fz += s[2][q][lane]; fn += s[3][q][lane];
        }
        float r = fast_sigmoid(fr + g1_bih[j] + g1_bhh[j]);
        float z = fast_sigmoid(fz + g1_bih[H2 + j] + g1_bhh[H2 + j]);
        float nn = fast_tanh(fn + g1_bih[2 * H2 + j] + r * g1_bhh[2 * H2 + j]);
        res1T[j * 64 + lane] = fs + bsc[j] + (1.0f - z) * nn;
    }
}

// ---- Stage 5: res2T = res1T + GRU2(res1,0)^T. Block per j; 8 waves split K=512.
__global__ __launch_bounds__(512) void k_h2(const float* __restrict__ res1T,
                                            const float* __restrict__ g2_ih,
                                            const float* __restrict__ g2_bih,
                                            const float* __restrict__ g2_bhh,
                                            float* __restrict__ res2T) {
    int j = blockIdx.x;
    int wv = threadIdx.x >> 6, lane = threadIdx.x & 63;
    int k0 = wv * 64;
    const float* wr = g2_ih + (size_t)j * H2 + k0;
    const float* wz = g2_ih + (size_t)(H2 + j) * H2 + k0;
    const float* wn = g2_ih + (size_t)(2 * H2 + j) * H2 + k0;
    const float* xT = res1T + k0 * 64;
    float pr = 0.0f, pz = 0.0f, pn = 0.0f;
    #pragma unroll 8
    for (int k = 0; k < 64; ++k) {
        float xv = xT[k * 64 + lane];
        pr += wr[k] * xv; pz += wz[k] * xv; pn += wn[k] * xv;
    }
    __shared__ float s[3][8][64];
    s[0][wv][lane] = pr; s[1][wv][lane] = pz; s[2][wv][lane] = pn;
    __syncthreads();
    if (wv == 0) {
        float fr = 0.0f, fz = 0.0f, fn = 0.0f;
        #pragma unroll
        for (int q = 0; q < 8; ++q) { fr += s[0][q][lane]; fz += s[1][q][lane]; fn += s[2][q][lane]; }
        float r = fast_sigmoid(fr + g2_bih[j] + g2_bhh[j]);
        float z = fast_sigmoid(fz + g2_bih[H2 + j] + g2_bhh[H2 + j]);
        float nn = fast_tanh(fn + g2_bih[2 * H2 + j] + r * g2_bhh[2 * H2 + j]);
        res2T[j * 64 + lane] = res1T[j * 64 + lane] + (1.0f - z) * nn;
    }
}

// ---- Stage 6: out[0..10240) = res2 @ wout.T + bout. Block per i; 8 waves split K=512.
__global__ __launch_bounds__(512) void k_out(const float* __restrict__ res2T,
                                             const float* __restrict__ wout,
                                             const float* __restrict__ bout,
                                             float* __restrict__ out) {
    int i = blockIdx.x;
    int wv = threadIdx.x >> 6, lane = threadIdx.x & 63;
    int k0 = wv * 64;
    const float* w = wout + (size_t)i * H2 + k0;
    const float* xT = res2T + k0 * 64;
    float p = 0.0f;
    #pragma unroll 8
    for (int k = 0; k < 64; ++k) p += w[k] * xT[k * 64 + lane];
    __shared__ float s[8][64];
    s[wv][lane] = p;
    __syncthreads();
    if (wv == 0) {
        float acc = 0.0f;
        #pragma unroll
        for (int q = 0; q < 8; ++q) acc += s[q][lane];
        out[lane * 160 + i] = acc + bout[i];
    }
}

extern "C" void kernel_launch(void* const* d_in, const int* in_sizes, int n_in,
                              void* d_out, int out_size, void* d_ws, size_t ws_size,
                              hipStream_t stream) {
    const float* input_enc      = (const float*)d_in[0];
    const float* input_attW_enc = (const float*)d_in[1];
    const float* input_dec      = (const float*)d_in[2];
    const float* style_vec      = (const float*)d_in[3];
    const int*   lengths_enc    = (const int*)d_in[4];
    const float* pw1  = (const float*)d_in[5];
    const float* pb1  = (const float*)d_in[6];
    const float* pw2  = (const float*)d_in[7];
    const float* pb2  = (const float*)d_in[8];
    const float* wdec = (const float*)d_in[9];
    const float* bdec = (const float*)d_in[10];
    const float* ga_ih  = (const float*)d_in[11];
    const float* ga_bih = (const float*)d_in[13];
    const float* ga_bhh = (const float*)d_in[14];
    const float* wattn  = (const float*)d_in[15];
    const float* battn  = (const float*)d_in[16];
    const float* wsc    = (const float*)d_in[17];
    const float* bsc    = (const float*)d_in[18];
    const float* g1_ih  = (const float*)d_in[19];
    const float* g1_bih = (const float*)d_in[21];
    const float* g1_bhh = (const float*)d_in[22];
    const float* g2_ih  = (const float*)d_in[23];
    const float* g2_bih = (const float*)d_in[25];
    const float* g2_bhh = (const float*)d_in[26];
    const float* wout   = (const float*)d_in[27];
    const float* bout   = (const float*)d_in[28];
    float* out = (float*)d_out;

    // workspace (floats); everything fully written before read — no zeroing needed
    float* ws = (float*)d_ws;
    float* num_part = ws;                         // CH*64*512 = 1048576
    float* den_part = ws + 1048576;               // CH*64    = 2048
    float* out_decT = ws + 1050624;               // 1152*64  = 73728
    float* attW_dec = ws + 1124352;               // 64*512   = 32768
    float* res1T    = ws + 1157120;               // 512*64   = 32768
    float* res2T    = ws + 1189888;               // 512*64   = 32768

    k_dec<<<64, 1024, 0, stream>>>(input_dec, style_vec, pw1, pb1, pw2, pb2,
                                   ga_ih, ga_bih, ga_bhh, wdec, bdec,
                                   out_decT, attW_dec);
    k_attn<<<dim3(CH, 32), 256, 0, stream>>>(input_enc, input_attW_enc, attW_dec,
                                             wattn, battn, lengths_enc, num_part, den_part);
    k_reduce<<<dim3(64, 2), 256, 0, stream>>>(num_part, den_part, out, out_decT);
    k_sc_h1<<<512, 512, 0, stream>>>(out_decT, wsc, bsc, g1_ih, g1_bih, g1_bhh, res1T);
    k_h2<<<512, 512, 0, stream>>>(res1T, g2_ih, g2_bih, g2_bhh, res2T);
    k_out<<<160, 512, 0, stream>>>(res2T, wout, bout, out);
}